// Round 2
// baseline (377.921 us; speedup 1.0000x reference)
//
#include <hip/hip_runtime.h>
#include <hip/hip_bf16.h>
#include <stdint.h>

// CrossAttention (B=4, N=M=4096, C=512), fp32 in/out, bf16 MFMA internally.
// Round 7 (resubmit; prior two rounds failed on infra, kernel never ran):
// expS pass moved from 128^2/2-phase gemm32 (~900 TF ceiling) to a 256^2
// 8-phase schedule (T2 LDS swizzle + T3/T4 counted vmcnt + T5 setprio).
//   Q    = rgb @ WqT^T (+bq)          [16384 x 512]        gemm32
//   K    = dep @ WkT^T (+bk)          [16384 x 512]        gemm32
//   Vt   = WvT @ dep^T (+bv row)      per batch [512x4096] gemm32
//   expS = exp(Q K^T / sqrt(C))       per batch [4096^2]   gemm256_exp (NEW)
//   O    = (expS @ Vt^T) / rowsum     per batch [4096x512] pv_gemm TM64xTN256

typedef unsigned short u16;
typedef __attribute__((ext_vector_type(8))) short bf16x8;
typedef __attribute__((ext_vector_type(16))) float f32x16;
typedef __attribute__((ext_vector_type(4))) unsigned short u16x4;

#define GLD_LDS16(g, l)                                                        \
  __builtin_amdgcn_global_load_lds(                                            \
      (const __attribute__((address_space(1))) unsigned int*)(g),              \
      (__attribute__((address_space(3))) unsigned int*)(l), 16, 0, 0)

__device__ __forceinline__ u16 f2bf(float f) {  // RNE f32 -> bf16
  unsigned x = __float_as_uint(f);
  return (u16)((x + 0x7fffu + ((x >> 16) & 1u)) >> 16);
}
__device__ __forceinline__ float bf2f(short s) {
  return __uint_as_float((unsigned)(unsigned short)s << 16);
}

// ---------------------------------------------------------------------------
// GEMM: C[M,N] = A[M,K]*B[N,K]^T, bf16 in, fp32 acc, 32x32x16 MFMA.
// 256 thr / 4 waves (2x2), TM x TN tile, BK=32, double-buffered LDS, one
// barrier per iter. XOR bank swizzle on 16-B k-chunks (R3: 0 conflicts).
// OUT_MODE: 0 = bf16, 1 = fp32. BIAS_MODE: 0 none, 1 bias[col], 2 bias[row].
// ---------------------------------------------------------------------------
template <int TM, int TN, int BIAS_MODE, int OUT_MODE, int MINW>
__global__ __launch_bounds__(256, MINW) void gemm32(
    const u16* __restrict__ A, const u16* __restrict__ Bm,
    const float* __restrict__ bias, void* __restrict__ Cv, int M, int N, int K,
    long long sAb, long long sBb, long long sCb, float scale) {
  constexpr int WROWS = TM / 2;
  constexpr int WCOLS = TN / 2;
  constexpr int MSUB = WROWS / 32;
  constexpr int NSUB = WCOLS / 32;
  constexpr int CA = TM / 64;  // A 16-row chunks per wave
  constexpr int CB = TN / 64;  // B 16-row chunks per wave

  const int bz = blockIdx.z;
  A += (size_t)bz * sAb;
  Bm += (size_t)bz * sBb;

  const int bm = blockIdx.y * TM;
  const int bn = blockIdx.x * TN;

  __shared__ u16 As[2][TM * 32];
  __shared__ u16 Bs[2][TN * 32];

  const int tid = threadIdx.x;
  const int wave = tid >> 6;
  const int lane = tid & 63;
  const int ln31 = lane & 31;
  const int half = lane >> 5;
  const int wr = wave >> 1;
  const int wc = wave & 1;

  const int rowA = lane >> 2;
  const int swz = ((lane & 3) ^ ((rowA + (rowA >> 2)) & 3)) * 8;
  const int gl = (ln31 + (ln31 >> 2)) & 3;

  f32x16 acc[MSUB][NSUB] = {};

  auto stage = [&](int buf, int k0) {
#pragma unroll
    for (int r = 0; r < CA; ++r) {
      const int ch = wave * CA + r;
      GLD_LDS16(A + (size_t)(bm + ch * 16 + rowA) * K + k0 + swz,
                As[buf] + ch * 16 * 32);
    }
#pragma unroll
    for (int r = 0; r < CB; ++r) {
      const int ch = wave * CB + r;
      GLD_LDS16(Bm + (size_t)(bn + ch * 16 + rowA) * K + k0 + swz,
                Bs[buf] + ch * 16 * 32);
    }
  };

  const int niter = K >> 5;
  stage(0, 0);
  for (int it = 0; it < niter; ++it) {
    __syncthreads();  // publishes buf it&1 (vmcnt drained here)
    if (it + 1 < niter) stage((it + 1) & 1, (it + 1) * 32);
    const int buf = it & 1;
#pragma unroll
    for (int kc = 0; kc < 2; ++kc) {
      const int p = ((kc * 2 + half) ^ gl) * 8;
      bf16x8 af[MSUB], bfv[NSUB];
#pragma unroll
      for (int mt = 0; mt < MSUB; ++mt)
        af[mt] =
            *(const bf16x8*)&As[buf][(wr * WROWS + mt * 32 + ln31) * 32 + p];
#pragma unroll
      for (int nt = 0; nt < NSUB; ++nt)
        bfv[nt] =
            *(const bf16x8*)&Bs[buf][(wc * WCOLS + nt * 32 + ln31) * 32 + p];
#pragma unroll
      for (int mt = 0; mt < MSUB; ++mt)
#pragma unroll
        for (int nt = 0; nt < NSUB; ++nt)
          acc[mt][nt] = __builtin_amdgcn_mfma_f32_32x32x16_bf16(
              af[mt], bfv[nt], acc[mt][nt], 0, 0, 0);
    }
  }

  // Epilogue. 32x32 C/D layout: col = lane&31, row = (r&3)+8*(r>>2)+4*half.
  const int crow0 = bm + wr * WROWS + 4 * half;
  const int ccol0 = bn + wc * WCOLS + ln31;
#pragma unroll
  for (int mt = 0; mt < MSUB; ++mt) {
#pragma unroll
    for (int nt = 0; nt < NSUB; ++nt) {
      const int col = ccol0 + nt * 32;
#pragma unroll
      for (int r = 0; r < 16; ++r) {
        const int row = crow0 + mt * 32 + (r & 3) + 8 * (r >> 2);
        float v = acc[mt][nt][r];
        if constexpr (BIAS_MODE == 1) v += bias[col];
        if constexpr (BIAS_MODE == 2) v += bias[row];
        const size_t idx = (size_t)bz * (size_t)sCb + (size_t)row * N + col;
        if constexpr (OUT_MODE == 0)
          ((u16*)Cv)[idx] = f2bf(v);
        else if constexpr (OUT_MODE == 1)
          ((float*)Cv)[idx] = v;
        else
          ((u16*)Cv)[idx] = f2bf(__expf(v * scale));
      }
    }
  }
}

// ---------------------------------------------------------------------------
// gemm256_exp: S[4096,4096] = exp(scale * Q[4096,512] K[4096,512]^T) in bf16.
// 256x256 tile, BK=64, 512 thr / 8 waves (2M x 4N), per-wave 128x64 output.
// 8-phase-style schedule: 4 quadrant-phases per K-tile; per phase
// {ds_read subtile; issue 2 global_load_lds for tile t+1; barrier;
//  lgkmcnt(0); setprio(1); 8 MFMA; setprio(0); vmcnt(counted); barrier}.
// Counted-vmcnt derivation (load order per tile: B0 B1 B2 B3 A0 A1 A2 A3;
// A-inst j holds exactly the rows phase j reads):
//   steady phase ends need [A1,A2,A3,nextB+A0] -> vmcnt 4,5,6,3 (never 0).
//   last tile (no prefetch): 2,1,0,0.
// LDS: rows of 64 bf16 (128 B); chunk XOR-swizzle c^(row&7) applied on the
// pre-swizzled GLOBAL source (global_load_lds dest is linear, m104/m173) and
// on the ds_read address -> 2 lanes/bank-slot per 16-lane group = free.
// Predicted: ~55-70 us for this dispatch, MfmaUtil ~55-62%, conflicts ~0.
// ---------------------------------------------------------------------------
#define XA_STGA(buf, j, k0)                                                    \
  GLD_LDS16(Ag + (size_t)((j) * 32 + (wv & 3) * 8 + (wv >> 2) * 128 + rlane) * \
                    512 +                                                      \
                (k0) + swz8,                                                   \
            &As[buf][((j) * 32 + (wv & 3) * 8 + (wv >> 2) * 128) * 64])
#define XA_STGB(buf, j, k0)                                                    \
  GLD_LDS16(Bg + (size_t)((j) * 64 + wv * 8 + rlane) * 512 + (k0) + swz8,      \
            &Bs[buf][((j) * 64 + wv * 8) * 64])

#define XA_PHASE(F, NV, PFS)                                                   \
  {                                                                            \
    bf16x8 af[4];                                                              \
    {                                                                          \
      const int arow = (wm * 128 + (F) * 32 + ln31) * 64;                      \
      _Pragma("unroll") for (int k = 0; k < 4; ++k) af[k] =                    \
          *(const bf16x8*)&As[p][arow + (((2 * k + half) ^ s7) << 3)];         \
    }                                                                          \
    if ((F) == 0) {                                                            \
      _Pragma("unroll") for (int n = 0; n < 2; ++n) {                          \
        const int brow = (wn * 64 + n * 32 + ln31) * 64;                       \
        _Pragma("unroll") for (int k = 0; k < 4; ++k) bfr[n][k] =              \
            *(const bf16x8*)&Bs[p][brow + (((2 * k + half) ^ s7) << 3)];       \
      }                                                                        \
    }                                                                          \
    PFS;                                                                       \
    __builtin_amdgcn_s_barrier();                                              \
    asm volatile("s_waitcnt lgkmcnt(0)" ::: "memory");                         \
    __builtin_amdgcn_sched_barrier(0);                                         \
    __builtin_amdgcn_s_setprio(1);                                             \
    _Pragma("unroll") for (int k = 0; k < 4; ++k) {                            \
      acc[F][0] = __builtin_amdgcn_mfma_f32_32x32x16_bf16(af[k], bfr[0][k],    \
                                                          acc[F][0], 0, 0, 0); \
      acc[F][1] = __builtin_amdgcn_mfma_f32_32x32x16_bf16(af[k], bfr[1][k],    \
                                                          acc[F][1], 0, 0, 0); \
    }                                                                          \
    __builtin_amdgcn_s_setprio(0);                                             \
    asm volatile("s_waitcnt vmcnt(" NV ")" ::: "memory");                      \
    __builtin_amdgcn_s_barrier();                                              \
    asm volatile("" ::: "memory");                                             \
  }

__global__ __launch_bounds__(512, 2) void gemm256_exp(
    const u16* __restrict__ Qm, const u16* __restrict__ Km,
    u16* __restrict__ Sout, long long sAb, long long sSb, float scale) {
  const int bz = blockIdx.z;
  const int bm = blockIdx.y * 256;
  const int bn = blockIdx.x * 256;
  const u16* Ag = Qm + (size_t)bz * (size_t)sAb + (size_t)bm * 512;
  const u16* Bg = Km + (size_t)bz * (size_t)sAb + (size_t)bn * 512;

  __shared__ u16 As[2][256 * 64];  // 64 KB
  __shared__ u16 Bs[2][256 * 64];  // 64 KB

  const int tid = threadIdx.x;
  const int wv = tid >> 6;    // wave 0..7
  const int lane = tid & 63;
  const int ln31 = lane & 31;
  const int half = lane >> 5;
  const int wm = wv >> 2;     // 0..1: 128-row half
  const int wn = wv & 3;      // 0..3: 64-col group
  const int rlane = lane >> 3;                 // staged row within 8-row chunk
  const int swz8 = ((lane & 7) ^ rlane) << 3;  // pre-swizzled global k-offset
  const int s7 = ln31 & 7;                     // ds_read swizzle key

  f32x16 acc[4][2] = {};
  bf16x8 bfr[2][4];

  // prologue: stage tile 0 into buf 0 (issue order B0..B3, A0..A3)
#pragma unroll
  for (int j = 0; j < 4; ++j) XA_STGB(0, j, 0);
#pragma unroll
  for (int j = 0; j < 4; ++j) XA_STGA(0, j, 0);
  asm volatile("s_waitcnt vmcnt(3)" ::: "memory");  // B0-3 + A0 landed
  __builtin_amdgcn_s_barrier();
  asm volatile("" ::: "memory");

  for (int t = 0; t < 7; ++t) {  // K = 512 -> 8 tiles of 64
    const int p = t & 1;
    const int q = p ^ 1;
    const int kn = (t + 1) << 6;
    XA_PHASE(0, "4", { XA_STGB(q, 0, kn); XA_STGB(q, 1, kn); });
    XA_PHASE(1, "5", { XA_STGB(q, 2, kn); XA_STGB(q, 3, kn); });
    XA_PHASE(2, "6", { XA_STGA(q, 0, kn); XA_STGA(q, 1, kn); });
    XA_PHASE(3, "3", { XA_STGA(q, 2, kn); XA_STGA(q, 3, kn); });
  }
  {  // last tile: no prefetch, drain progressively
    const int p = 1;
    XA_PHASE(0, "2", {});
    XA_PHASE(1, "1", {});
    XA_PHASE(2, "0", {});
    XA_PHASE(3, "0", {});
  }

  // epilogue: exp + bf16 store. 32x32 layout: col=lane&31, row=(r&3)+8*(r>>2)+4*half.
  const size_t ob = (size_t)bz * (size_t)sSb;
  const int c0 = bn + wn * 64 + ln31;
  const int r0 = bm + wm * 128 + 4 * half;
#pragma unroll
  for (int m = 0; m < 4; ++m) {
#pragma unroll
    for (int n = 0; n < 2; ++n) {
      const int col = c0 + n * 32;
#pragma unroll
      for (int r = 0; r < 16; ++r) {
        const int row = r0 + m * 32 + (r & 3) + 8 * (r >> 2);
        Sout[ob + (size_t)row * 4096 + col] = f2bf(__expf(acc[m][n][r] * scale));
      }
    }
  }
}

// ---------------------------------------------------------------------------
// PV: O[64 q x 256 d] = (expS_slab @ Vt^T) / den. 256 thr / 4 waves, each
// wave owns a 64-d group; all waves share the same 64 q rows, so den[row] =
// register rowsum of the (shared) A-fragments — no atomics, no extra pass.
// Double-buffered; grid (2,64,4) = 512 blocks = 2/CU for cross-block overlap.
// ---------------------------------------------------------------------------
__global__ __launch_bounds__(256, 2) void pv_gemm(
    const u16* __restrict__ P, const u16* __restrict__ Vt,
    float* __restrict__ O) {
  const int bz = blockIdx.z;
  const u16* A = P + (size_t)bz * (4096ull * 4096ull);
  const u16* B = Vt + (size_t)bz * (512ull * 4096ull);
  float* Ob = O + (size_t)bz * (4096ull * 512ull);

  const int bm = blockIdx.y * 64;   // q-row slab
  const int bn = blockIdx.x * 256;  // d half

  __shared__ u16 As[2][64 * 32];   // 2 x 4 KB
  __shared__ u16 Bs[2][256 * 32];  // 2 x 16 KB
  __shared__ float den_s[64];

  const int tid = threadIdx.x;
  const int wave = tid >> 6;  // d-group 0..3
  const int lane = tid & 63;
  const int ln31 = lane & 31;
  const int half = lane >> 5;

  const int rowA = lane >> 2;
  const int swz = ((lane & 3) ^ ((rowA + (rowA >> 2)) & 3)) * 8;
  const int gl = (ln31 + (ln31 >> 2)) & 3;

  f32x16 acc[2][2] = {};
  float rsum[2] = {0.f, 0.f};

  auto stage = [&](int buf, int k0) {
    // A: 4 chunks of 16 rows, one per wave (HBM-cold — issue first).
    GLD_LDS16(A + (size_t)(bm + wave * 16 + rowA) * 4096 + k0 + swz,
              As[buf] + wave * 16 * 32);
    // B: 16 chunks, 4 per wave (L2-resident Vt).
#pragma unroll
    for (int r = 0; r < 4; ++r) {
      const int ch = wave * 4 + r;
      GLD_LDS16(B + (size_t)(bn + ch * 16 + rowA) * 4096 + k0 + swz,
                Bs[buf] + ch * 16 * 32);
    }
  };

  stage(0, 0);
  for (int it = 0; it < 128; ++it) {
    __syncthreads();
    if (it + 1 < 128) stage((it + 1) & 1, (it + 1) * 32);
    const int buf = it & 1;
#pragma unroll
    for (int kc = 0; kc < 2; ++kc) {
      const int p = ((kc * 2 + half) ^ gl) * 8;
      bf16x8 af[2], bfv[2];
#pragma unroll
      for (int mt = 0; mt < 2; ++mt)
        af[mt] = *(const bf16x8*)&As[buf][(mt * 32 + ln31) * 32 + p];
#pragma unroll
      for (int nt = 0; nt < 2; ++nt)
        bfv[nt] =
            *(const bf16x8*)&Bs[buf][(wave * 64 + nt * 32 + ln31) * 32 + p];
#pragma unroll
      for (int mt = 0; mt < 2; ++mt) {
#pragma unroll
        for (int j = 0; j < 8; ++j) rsum[mt] += bf2f(af[mt][j]);
#pragma unroll
        for (int nt = 0; nt < 2; ++nt)
          acc[mt][nt] = __builtin_amdgcn_mfma_f32_32x32x16_bf16(
              af[mt], bfv[nt], acc[mt][nt], 0, 0, 0);
      }
    }
  }

  // den: lane (ln31, half) holds the row sum of q-row mt*32+ln31 over its
  // k-half; combine halves; wave 0 publishes (all waves hold identical A).
#pragma unroll
  for (int mt = 0; mt < 2; ++mt) rsum[mt] += __shfl_xor(rsum[mt], 32, 64);
  __syncthreads();
  if (wave == 0 && half == 0) {
    den_s[ln31] = rsum[0];
    den_s[32 + ln31] = rsum[1];
  }
  __syncthreads();

  const int crow0 = 4 * half;
  const int ccol0 = bn + wave * 64 + ln31;
#pragma unroll
  for (int mt = 0; mt < 2; ++mt) {
#pragma unroll
    for (int r = 0; r < 16; ++r) {
      const int rl = crow0 + mt * 32 + (r & 3) + 8 * (r >> 2);
      const float rd = 1.0f / den_s[rl];
#pragma unroll
      for (int nt = 0; nt < 2; ++nt)
        Ob[(size_t)(bm + rl) * 512 + ccol0 + nt * 32] = acc[mt][nt][r] * rd;
    }
  }
}

// ---------------------------------------------------------------------------
__global__ __launch_bounds__(256) void cvt_pair(const float* __restrict__ x,
                                                const float* __restrict__ y,
                                                u16* __restrict__ ox,
                                                u16* __restrict__ oy, int n4) {
  const int i = blockIdx.x * 256 + threadIdx.x;
  if (i >= n4) return;
  const float4 a = ((const float4*)x)[i];
  const float4 b = ((const float4*)y)[i];
  u16x4 oa, ob;
  oa[0] = f2bf(a.x); oa[1] = f2bf(a.y); oa[2] = f2bf(a.z); oa[3] = f2bf(a.w);
  ob[0] = f2bf(b.x); ob[1] = f2bf(b.y); ob[2] = f2bf(b.z); ob[3] = f2bf(b.w);
  ((u16x4*)ox)[i] = oa;
  ((u16x4*)oy)[i] = ob;
}

// ---------------------------------------------------------------------------
__global__ __launch_bounds__(256) void wtrans_k(const float* __restrict__ W,
                                                u16* __restrict__ WT) {
  const int tr = blockIdx.y * 64;
  const int tc = blockIdx.x * 64;
  __shared__ float T[64][65];
  const int t = threadIdx.x;
  const int r0 = t >> 4;
  const int c0 = (t & 15) * 4;
#pragma unroll
  for (int rr = 0; rr < 4; ++rr) {
    const int row = rr * 16 + r0;
    const float4 w = *(const float4*)&W[(size_t)(tr + row) * 512 + tc + c0];
    T[row][c0 + 0] = w.x; T[row][c0 + 1] = w.y;
    T[row][c0 + 2] = w.z; T[row][c0 + 3] = w.w;
  }
  __syncthreads();
#pragma unroll
  for (int rr = 0; rr < 4; ++rr) {
    const int orow = rr * 16 + r0;
    u16x4 o;
#pragma unroll
    for (int j = 0; j < 4; ++j) o[j] = f2bf(T[c0 + j][orow]);
    *(u16x4*)&WT[(size_t)(tc + orow) * 512 + tr + c0] = o;
  }
}

// ---------------------------------------------------------------------------
extern "C" void kernel_launch(void* const* d_in, const int* in_sizes, int n_in,
                              void* d_out, int out_size, void* d_ws,
                              size_t ws_size, hipStream_t stream) {
  const float* rgb = (const float*)d_in[0];
  const float* dep = (const float*)d_in[1];
  const float* Wq = (const float*)d_in[2];
  const float* bq = (const float*)d_in[3];
  const float* Wk = (const float*)d_in[4];
  const float* bk = (const float*)d_in[5];
  const float* Wv = (const float*)d_in[6];
  const float* bv = (const float*)d_in[7];
  float* out = (float*)d_out;

  const int B = 4, N = 4096, M = 4096, C = 512;
  const size_t nBNC = (size_t)B * N * C;
  const float scale = 0.044194173824159216f;  // 512^-0.5

  char* ws = (char*)d_ws;
  size_t off = 0;
  auto carve = [&](size_t bytes) -> void* {
    void* p = ws + off;
    off += (bytes + 255) & ~(size_t)255;
    return p;
  };
  u16* rgb_bf = (u16*)carve(nBNC * 2);
  u16* dep_bf = (u16*)carve(nBNC * 2);
  u16* WqT = (u16*)carve((size_t)C * C * 2);
  u16* WkT = (u16*)carve((size_t)C * C * 2);
  u16* WvT = (u16*)carve((size_t)C * C * 2);
  u16* Qb = (u16*)carve(nBNC * 2);
  u16* Kb = (u16*)carve(nBNC * 2);
  u16* Vt = (u16*)carve(nBNC * 2);
  u16* Sb = (u16*)carve((size_t)B * N * M * 2);  // 134 MB expS

  const long long strQ = (long long)N * C;  // 2,097,152
  const long long strS = (long long)N * M;  // 16,777,216
  const long long strV = (long long)C * M;  // 2,097,152

  // 0) conversions
  cvt_pair<<<8192, 256, 0, stream>>>(rgb, dep, rgb_bf, dep_bf, (int)(nBNC / 4));
  wtrans_k<<<dim3(8, 8), 256, 0, stream>>>(Wq, WqT);
  wtrans_k<<<dim3(8, 8), 256, 0, stream>>>(Wk, WkT);
  wtrans_k<<<dim3(8, 8), 256, 0, stream>>>(Wv, WvT);

  // 1) projections
  gemm32<128, 128, 1, 0, 4><<<dim3(4, 128, 1), 256, 0, stream>>>(
      rgb_bf, WqT, bq, Qb, 16384, 512, 512, 0, 0, 0, 1.f);
  gemm32<128, 128, 1, 0, 4><<<dim3(4, 128, 1), 256, 0, stream>>>(
      dep_bf, WkT, bk, Kb, 16384, 512, 512, 0, 0, 0, 1.f);
  gemm32<128, 128, 2, 0, 4><<<dim3(32, 4, 4), 256, 0, stream>>>(
      WvT, dep_bf, bv, Vt, 512, 4096, 512, 0, strQ, strV, 1.f);

  // 2) expS = exp(Q K^T * scale)  — 256^2 8-phase schedule
  gemm256_exp<<<dim3(16, 16, 4), 512, 0, stream>>>(Qb, Kb, Sb, strQ, strS,
                                                   scale);

  // 3) O = expS @ Vt^T / rowsum(expS)   (den computed in-block)
  pv_gemm<<<dim3(2, 64, 4), 256, 0, stream>>>(Sb, Vt, out);
}